// Round 2
// baseline (901.178 us; speedup 1.0000x reference)
//
#include <hip/hip_runtime.h>
#include <type_traits>
#include <utility>

// ---------------------------------------------------------------------------
// HyenaFilter: y[b,c,l] = sum_{j<=l} k[c,j] x[b,c,l-j] + bias[c] x[b,c,l]
// k generated by sin-MLP on z + exponential modulation.
// Strategy: direct causal conv as bf16 MFMA (32x32x16), one workgroup/channel,
// whole channel (4 batch rows of x, reversed filter w/ 4 shifted replicas) in LDS.
// R1 fix: add the Delta=-16 chunk (n=-1). Rows i>=16 of each 32-tile need
// source positions s in [L0+16, L0+i] (filter taps k[0..15]); the n>=0 loop
// never covered them -> absmax 18.9 from up to 16 missing undecayed terms.
// ---------------------------------------------------------------------------

typedef __attribute__((ext_vector_type(4))) short  short4v;
typedef __attribute__((ext_vector_type(8))) short  short8v;
typedef __attribute__((ext_vector_type(8))) __bf16 bf16x8;
typedef __attribute__((ext_vector_type(16))) float f32x16;

// --- MFMA builtin operand-type hedge (short8 vs v8bf16) --------------------
template <typename V, typename = void> struct MfmaTakes : std::false_type {};
template <typename V>
struct MfmaTakes<V, std::void_t<decltype(__builtin_amdgcn_mfma_f32_32x32x16_bf16(
    std::declval<V>(), std::declval<V>(), std::declval<f32x16>(), 0, 0, 0))>>
    : std::true_type {};

template <bool UseBf16> struct MfmaImpl;
template <> struct MfmaImpl<true> {
  template <typename V>
  static __device__ inline f32x16 run(V a, V b, f32x16 c) {
    return __builtin_amdgcn_mfma_f32_32x32x16_bf16(
        __builtin_bit_cast(bf16x8, a), __builtin_bit_cast(bf16x8, b), c, 0, 0, 0);
  }
};
template <> struct MfmaImpl<false> {
  template <typename V>
  static __device__ inline f32x16 run(V a, V b, f32x16 c) {
    return __builtin_amdgcn_mfma_f32_32x32x16_bf16(a, b, c, 0, 0, 0);
  }
};

__device__ inline f32x16 mfma_bf16(short8v a, short8v b, f32x16 c) {
  return MfmaImpl<MfmaTakes<bf16x8>::value>::run(a, b, c);
}

// float -> bf16 bits, round-to-nearest-even (finite values only)
__device__ inline short f2bf(float f) {
  unsigned int u = __builtin_bit_cast(unsigned int, f);
  u += 0x7FFFu + ((u >> 16) & 1u);
  return (short)(u >> 16);
}

// ---------------------------------------------------------------------------
// Kernel 1: filter generation.  gk[c*8192 + l] = bf16(k[c,l])
// grid 256 blocks x 256 thr; block handles 32 consecutive l.
// ---------------------------------------------------------------------------
__global__ __launch_bounds__(256) void hyena_filter(
    const float* __restrict__ z, const float* __restrict__ deltas,
    const float* __restrict__ W0, const float* __restrict__ b0,
    const float* __restrict__ W1, const float* __restrict__ b1,
    const float* __restrict__ W2, const float* __restrict__ b2,
    const float* __restrict__ freq, const float* __restrict__ Wout,
    short* __restrict__ gk) {
  __shared__ float zt[32][33];
  __shared__ float hA[32][64];
  __shared__ float hB[32][64];
  const int tid = threadIdx.x;
  const int l0 = blockIdx.x << 5;

  for (int i = tid; i < 32 * 33; i += 256) {
    int l = i / 33, e = i - l * 33;
    zt[l][e] = z[(l0 + l) * 33 + e];
  }
  __syncthreads();
  // h1 = sin(freq * (z@W0 + b0))
  for (int i = tid; i < 2048; i += 256) {
    int l = i >> 6, o = i & 63;
    float s = b0[o];
    for (int e = 0; e < 33; ++e) s += zt[l][e] * W0[e * 64 + o];
    hA[l][o] = sinf(freq[o] * s);
  }
  __syncthreads();
  // h2
  for (int i = tid; i < 2048; i += 256) {
    int l = i >> 6, o = i & 63;
    float s = b1[o];
    for (int e = 0; e < 64; ++e) s += hA[l][e] * W1[e * 64 + o];
    hB[l][o] = sinf(freq[o] * s);
  }
  __syncthreads();
  // h3
  for (int i = tid; i < 2048; i += 256) {
    int l = i >> 6, o = i & 63;
    float s = b2[o];
    for (int e = 0; e < 64; ++e) s += hB[l][e] * W2[e * 64 + o];
    hA[l][o] = sinf(freq[o] * s);
  }
  __syncthreads();
  // k0 = h3 @ Wout, then exponential modulation; store bf16 transposed [c][l]
  for (int c0 = tid; c0 < 768; c0 += 256) {
    float a32[32];
#pragma unroll
    for (int l = 0; l < 32; ++l) a32[l] = 0.f;
    for (int o = 0; o < 64; ++o) {
      float w = Wout[o * 768 + c0];
#pragma unroll
      for (int l = 0; l < 32; ++l) a32[l] += hA[l][o] * w;
    }
    float del = fabsf(deltas[c0]);
    unsigned int* gku = reinterpret_cast<unsigned int*>(gk + (c0 << 13) + l0);
#pragma unroll
    for (int l = 0; l < 32; l += 2) {
      float t0 = (float)(l0 + l) * (1.f / 8191.f);
      float t1 = (float)(l0 + l + 1) * (1.f / 8191.f);
      unsigned short v0 = (unsigned short)f2bf(a32[l] * expf(-t0 * del));
      unsigned short v1 = (unsigned short)f2bf(a32[l + 1] * expf(-t1 * del));
      gku[l >> 1] = (unsigned int)v0 | ((unsigned int)v1 << 16);
    }
  }
}

// ---------------------------------------------------------------------------
// Kernel 2: causal conv via MFMA. One block (256 thr = 4 waves) per channel.
//
// LDS: sKR[rho][u] = KR[u+rho], KR[t] = k[8207-t] (t in [16,8207]) else 0.
//      sXB[b][256+s] = bf16(x[b,c,s]), 256 left zeros for causal boundary.
// A-frag:  A[i][m] = k[Delta+i-m]  -> KR[8207-Delta-i+base .. +7] ascending,
//          replica rho = addr&3 gives two aligned ds_read_b64.
// B-frag:  B[m][n] = x[b_n, O_a + 32*t_n - Delta + m], aligned ds_read_b128.
// D (32x32): col=lane&31 -> (t=col>>2, b=col&3), row=(r&3)+8*(r>>2)+4*(lane>>5).
// Wave w handles super-groups {w, 7-w} (1024 outputs x 4 batch each), Nacc=4.
// Delta runs over 16*n for n = -1..nsteps-1 (n=-1 covers rows 16..31's
// newest taps; causal zeros come from the KR pad).
// ---------------------------------------------------------------------------
__global__ __launch_bounds__(256, 1) void hyena_conv(
    const float* __restrict__ x, const float* __restrict__ bias,
    const short* __restrict__ gk, float* __restrict__ out) {
  __shared__ __align__(16) short sKR[4][8240];  // 65920 B
  __shared__ __align__(16) short sXB[4][8456];  // 67648 B (8448 data + 8 pad)
  const int c = blockIdx.x;
  const int tid = threadIdx.x;

  // stage x -> bf16 LDS rows (with 256 leading zeros)
  for (int b = 0; b < 4; ++b) {
    const float* xr = x + ((b * 768 + c) << 13);
    for (int p = tid; p < 8448; p += 256) {
      short v = 0;
      if (p >= 256) v = f2bf(xr[p - 256]);
      sXB[b][p] = v;
    }
  }
  // stage reversed filter, 4 shifted replicas
  {
    const short* gkr = gk + (c << 13);
    for (int r = 0; r < 4; ++r)
      for (int u = tid; u < 8240; u += 256) {
        int t = u + r;
        short v = 0;
        if (t >= 16 && t <= 8207) v = gkr[8207 - t];
        sKR[r][u] = v;
      }
  }
  __syncthreads();

  const int lane = tid & 63;
  const int wid  = tid >> 6;
  const int i31  = lane & 31;
  const int half = lane >> 5;
  const int base = half << 3;
  const int tcol = i31 >> 2;
  const int bcol = i31 & 3;
  const float bc = bias[c];

  for (int gsel = 0; gsel < 2; ++gsel) {
    const int g = gsel ? (7 - wid) : wid;
    const int Og = g << 10;
    const int nsteps = (g << 6) + 63;

    f32x16 acc[4];
#pragma unroll
    for (int a = 0; a < 4; ++a)
#pragma unroll
      for (int r = 0; r < 16; ++r) acc[a][r] = 0.f;

    const int af0 = 8207 - i31 + base;
    const int pb0 = 256 + Og + (tcol << 5) + base;

#pragma unroll 2
    for (int n = -1; n < nsteps; ++n) {
      const int dl = n * 16;
      const int aoff = af0 - dl;
      const int rho = aoff & 3;
      const int u0 = aoff & ~3;
      const short4v* ap = reinterpret_cast<const short4v*>(&sKR[rho][u0]);
      const short4v alo = ap[0];
      const short4v ahi = ap[1];
      short8v av;
      av[0] = alo[0]; av[1] = alo[1]; av[2] = alo[2]; av[3] = alo[3];
      av[4] = ahi[0]; av[5] = ahi[1]; av[6] = ahi[2]; av[7] = ahi[3];
      const int pb = pb0 - dl;
#pragma unroll
      for (int a = 0; a < 4; ++a) {
        if (n <= (g << 6) + (a << 4) + 14) {  // Delta <= O_a + 239 (wave-uniform)
          const short8v bv =
              *reinterpret_cast<const short8v*>(&sXB[bcol][pb + (a << 8)]);
          acc[a] = mfma_bf16(av, bv, acc[a]);
        }
      }
    }

    // epilogue: y = acc + bias*x
#pragma unroll
    for (int a = 0; a < 4; ++a) {
      const int lb = Og + (a << 8) + (tcol << 5) + (half << 2);
#pragma unroll
      for (int r = 0; r < 16; ++r) {
        const int row = (r & 3) + ((r >> 2) << 3);
        const int l = lb + row;
        const int idx = ((bcol * 768 + c) << 13) + l;
        out[idx] = acc[a][r] + bc * x[idx];
      }
    }
  }
}

// ---------------------------------------------------------------------------
extern "C" void kernel_launch(void* const* d_in, const int* in_sizes, int n_in,
                              void* d_out, int out_size, void* d_ws, size_t ws_size,
                              hipStream_t stream) {
  const float* x      = (const float*)d_in[0];
  const float* bias   = (const float*)d_in[1];
  const float* z      = (const float*)d_in[2];
  const float* deltas = (const float*)d_in[3];
  const float* W0     = (const float*)d_in[4];
  const float* b0     = (const float*)d_in[5];
  const float* W1     = (const float*)d_in[6];
  const float* b1     = (const float*)d_in[7];
  const float* W2     = (const float*)d_in[8];
  const float* b2     = (const float*)d_in[9];
  const float* freq   = (const float*)d_in[10];
  const float* Wout   = (const float*)d_in[11];
  float* out = (float*)d_out;
  short* gk = (short*)d_ws;  // 768*8192*2 B = 12.6 MB filter workspace

  hipLaunchKernelGGL(hyena_filter, dim3(256), dim3(256), 0, stream,
                     z, deltas, W0, b0, W1, b1, W2, b2, freq, Wout, gk);
  hipLaunchKernelGGL(hyena_conv, dim3(768), dim3(256), 0, stream,
                     x, bias, gk, out);
}

// Round 3
// 524.521 us; speedup vs baseline: 1.7181x; 1.7181x over previous
//
#include <hip/hip_runtime.h>
#include <type_traits>
#include <utility>

// ---------------------------------------------------------------------------
// HyenaFilter: y[b,c,l] = sum_{j<=l} k[c,j] x[b,c,l-j] + bias[c] x[b,c,l]
// Direct causal conv as bf16 MFMA 32x32x16, one 1024-thread block per channel.
// R3: latency-bound fix. 16 waves/block (4/SIMD), branchless inner loop
// (zero-pad absorbs formerly-guarded iterations), strength-reduced LDS
// pointers, epilogue x from LDS. g-groups of 512 outputs, Nacc=2,
// g = wid<8 ? wid : 23-wid balances per-SIMD work exactly (sum g+1 = 34).
// ---------------------------------------------------------------------------

typedef __attribute__((ext_vector_type(4))) short  short4v;
typedef __attribute__((ext_vector_type(8))) short  short8v;
typedef __attribute__((ext_vector_type(8))) __bf16 bf16x8;
typedef __attribute__((ext_vector_type(16))) float f32x16;

// --- MFMA builtin operand-type hedge (short8 vs v8bf16) --------------------
template <typename V, typename = void> struct MfmaTakes : std::false_type {};
template <typename V>
struct MfmaTakes<V, std::void_t<decltype(__builtin_amdgcn_mfma_f32_32x32x16_bf16(
    std::declval<V>(), std::declval<V>(), std::declval<f32x16>(), 0, 0, 0))>>
    : std::true_type {};

template <bool UseBf16> struct MfmaImpl;
template <> struct MfmaImpl<true> {
  template <typename V>
  static __device__ inline f32x16 run(V a, V b, f32x16 c) {
    return __builtin_amdgcn_mfma_f32_32x32x16_bf16(
        __builtin_bit_cast(bf16x8, a), __builtin_bit_cast(bf16x8, b), c, 0, 0, 0);
  }
};
template <> struct MfmaImpl<false> {
  template <typename V>
  static __device__ inline f32x16 run(V a, V b, f32x16 c) {
    return __builtin_amdgcn_mfma_f32_32x32x16_bf16(a, b, c, 0, 0, 0);
  }
};

__device__ inline f32x16 mfma_bf16(short8v a, short8v b, f32x16 c) {
  return MfmaImpl<MfmaTakes<bf16x8>::value>::run(a, b, c);
}

// float -> bf16 bits, round-to-nearest-even (finite values only)
__device__ inline short f2bf(float f) {
  unsigned int u = __builtin_bit_cast(unsigned int, f);
  u += 0x7FFFu + ((u >> 16) & 1u);
  return (short)(u >> 16);
}
__device__ inline float bf2f(short s) {
  unsigned int u = ((unsigned int)(unsigned short)s) << 16;
  return __builtin_bit_cast(float, u);
}

// ---------------------------------------------------------------------------
// Kernel 1: filter generation.  gk[c*8192 + l] = bf16(k[c,l])
// ---------------------------------------------------------------------------
__global__ __launch_bounds__(256) void hyena_filter(
    const float* __restrict__ z, const float* __restrict__ deltas,
    const float* __restrict__ W0, const float* __restrict__ b0,
    const float* __restrict__ W1, const float* __restrict__ b1,
    const float* __restrict__ W2, const float* __restrict__ b2,
    const float* __restrict__ freq, const float* __restrict__ Wout,
    short* __restrict__ gk) {
  __shared__ float zt[32][33];
  __shared__ float hA[32][64];
  __shared__ float hB[32][64];
  const int tid = threadIdx.x;
  const int l0 = blockIdx.x << 5;

  for (int i = tid; i < 32 * 33; i += 256) {
    int l = i / 33, e = i - l * 33;
    zt[l][e] = z[(l0 + l) * 33 + e];
  }
  __syncthreads();
  for (int i = tid; i < 2048; i += 256) {
    int l = i >> 6, o = i & 63;
    float s = b0[o];
    for (int e = 0; e < 33; ++e) s += zt[l][e] * W0[e * 64 + o];
    hA[l][o] = sinf(freq[o] * s);
  }
  __syncthreads();
  for (int i = tid; i < 2048; i += 256) {
    int l = i >> 6, o = i & 63;
    float s = b1[o];
    for (int e = 0; e < 64; ++e) s += hA[l][e] * W1[e * 64 + o];
    hB[l][o] = sinf(freq[o] * s);
  }
  __syncthreads();
  for (int i = tid; i < 2048; i += 256) {
    int l = i >> 6, o = i & 63;
    float s = b2[o];
    for (int e = 0; e < 64; ++e) s += hB[l][e] * W2[e * 64 + o];
    hA[l][o] = sinf(freq[o] * s);
  }
  __syncthreads();
  for (int c0 = tid; c0 < 768; c0 += 256) {
    float a32[32];
#pragma unroll
    for (int l = 0; l < 32; ++l) a32[l] = 0.f;
    for (int o = 0; o < 64; ++o) {
      float w = Wout[o * 768 + c0];
#pragma unroll
      for (int l = 0; l < 32; ++l) a32[l] += hA[l][o] * w;
    }
    float del = fabsf(deltas[c0]);
    unsigned int* gku = reinterpret_cast<unsigned int*>(gk + (c0 << 13) + l0);
#pragma unroll
    for (int l = 0; l < 32; l += 2) {
      float t0 = (float)(l0 + l) * (1.f / 8191.f);
      float t1 = (float)(l0 + l + 1) * (1.f / 8191.f);
      unsigned short v0 = (unsigned short)f2bf(a32[l] * expf(-t0 * del));
      unsigned short v1 = (unsigned short)f2bf(a32[l + 1] * expf(-t1 * del));
      gku[l >> 1] = (unsigned int)v0 | ((unsigned int)v1 << 16);
    }
  }
}

// ---------------------------------------------------------------------------
// Kernel 2: causal conv via MFMA. 1024 threads (16 waves) per channel.
//
// LDS: sKR[rho][u] = KR[u+rho], KR[t] = k[8207-t] for t in [16,8207] else 0.
//      sXB[b][496+s] = bf16(x[b,c,s]); [0,496) zero (absorbs "future" chunks
//      whose B reads fall left of the data), [8688,8712) bank pad.
//      sXB row = 8712 shorts -> 4356 dw == 4 (mod 32): bcol/tcol lanes land
//      on distinct bank groups (same layout class R2 measured 0 conflicts).
// Wave wid -> g = wid<8 ? wid : 23-wid (SIMD-balanced). Og = g*512.
// Per iter (it = 0..32g+32): Delta = 16(it-1);
//   A[i][m] = k[Delta+i-m]: two b64 at kb[u] / kb[u+4], u = u00+16-16it
//   B[m][n] = x[bcol, Oa + 32t - Delta + m]: b128 at xb[p], xb[p+256]
//   acc[a] = mfma(av, bv[a], acc[a]); all unconditional, single basic block.
// ---------------------------------------------------------------------------
__global__ __launch_bounds__(1024, 4) void hyena_conv(
    const float* __restrict__ x, const float* __restrict__ bias,
    const short* __restrict__ gk, float* __restrict__ out) {
  __shared__ __align__(16) short sKR[4][8240];  // 65920 B
  __shared__ __align__(16) short sXB[4][8712];  // 69696 B
  const int c = blockIdx.x;
  const int tid = threadIdx.x;

  // stage x -> bf16 LDS rows (496 leading zeros, 24 tail pad)
  for (int b = 0; b < 4; ++b) {
    const float* xr = x + ((b * 768 + c) << 13);
    for (int p = tid; p < 8712; p += 1024) {
      short v = 0;
      if (p >= 496 && p < 8688) v = f2bf(xr[p - 496]);
      sXB[b][p] = v;
    }
  }
  // stage reversed filter, 4 shifted replicas
  {
    const short* gkr = gk + (c << 13);
    for (int r = 0; r < 4; ++r)
      for (int u = tid; u < 8240; u += 1024) {
        int t = u + r;
        short v = 0;
        if (t >= 16 && t <= 8207) v = gkr[8207 - t];
        sKR[r][u] = v;
      }
  }
  __syncthreads();

  const int lane = tid & 63;
  const int wid  = tid >> 6;                      // 0..15
  const int g    = (wid < 8) ? wid : (23 - wid);  // SIMD-balanced mapping
  const int i31  = lane & 31;
  const int half = lane >> 5;
  const int base = half << 3;
  const int tcol = i31 >> 2;
  const int bcol = i31 & 3;
  const float bc = bias[c];

  const int Og    = g << 9;
  const int niter = (g << 5) + 33;

  f32x16 acc0, acc1;
#pragma unroll
  for (int r = 0; r < 16; ++r) { acc0[r] = 0.f; acc1[r] = 0.f; }

  const int af0 = 8207 - i31 + base;
  const int rho = af0 & 3;
  const int u00 = af0 & ~3;
  const int pb0 = 496 + Og + (tcol << 5) + base;

  const short* ap = &sKR[rho][u00 + 16];
  const short* bp = &sXB[bcol][pb0 + 16];

#pragma unroll 2
  for (int it = 0; it < niter; ++it) {
    const short4v alo = *reinterpret_cast<const short4v*>(ap);
    const short4v ahi = *reinterpret_cast<const short4v*>(ap + 4);
    short8v av;
    av[0] = alo[0]; av[1] = alo[1]; av[2] = alo[2]; av[3] = alo[3];
    av[4] = ahi[0]; av[5] = ahi[1]; av[6] = ahi[2]; av[7] = ahi[3];
    const short8v bv0 = *reinterpret_cast<const short8v*>(bp);
    const short8v bv1 = *reinterpret_cast<const short8v*>(bp + 256);
    acc0 = mfma_bf16(av, bv0, acc0);
    acc1 = mfma_bf16(av, bv1, acc1);
    ap -= 16;
    bp -= 16;
  }

  // epilogue: y = acc + bias*x  (x read back from LDS as bf16)
#pragma unroll
  for (int a = 0; a < 2; ++a) {
    const f32x16& acc = a ? acc1 : acc0;
    const int lb = Og + (a << 8) + (tcol << 5) + (half << 2);
#pragma unroll
    for (int r = 0; r < 16; ++r) {
      const int row = (r & 3) + ((r >> 2) << 3);
      const int l = lb + row;
      const float xv = bf2f(sXB[bcol][496 + l]);
      out[((bcol * 768 + c) << 13) + l] = acc[r] + bc * xv;
    }
  }
}

// ---------------------------------------------------------------------------
extern "C" void kernel_launch(void* const* d_in, const int* in_sizes, int n_in,
                              void* d_out, int out_size, void* d_ws, size_t ws_size,
                              hipStream_t stream) {
  const float* x      = (const float*)d_in[0];
  const float* bias   = (const float*)d_in[1];
  const float* z      = (const float*)d_in[2];
  const float* deltas = (const float*)d_in[3];
  const float* W0     = (const float*)d_in[4];
  const float* b0     = (const float*)d_in[5];
  const float* W1     = (const float*)d_in[6];
  const float* b1     = (const float*)d_in[7];
  const float* W2     = (const float*)d_in[8];
  const float* b2     = (const float*)d_in[9];
  const float* freq   = (const float*)d_in[10];
  const float* Wout   = (const float*)d_in[11];
  float* out = (float*)d_out;
  short* gk = (short*)d_ws;  // 768*8192*2 B = 12.6 MB filter workspace

  hipLaunchKernelGGL(hyena_filter, dim3(256), dim3(256), 0, stream,
                     z, deltas, W0, b0, W1, b1, W2, b2, freq, Wout, gk);
  hipLaunchKernelGGL(hyena_conv, dim3(768), dim3(1024), 0, stream,
                     x, bias, gk, out);
}